// Round 1
// 512.052 us; speedup vs baseline: 1.0245x; 1.0245x over previous
//
#include <hip/hip_runtime.h>

// EMA MagNorm, exact two-pass chunked-scan decomposition.
// mu_t = a*mu + (1-a)*x_t; var_t = a*var + (1-a)*(x_t-mu_t)^2;
// y_t = (x_t-mu_t)/(sqrt(var_t)+eps).  B=32, T=4096, F=481, fp32.
//
// R3: replace W=512 redundant warm-up (1.6x HBM over-fetch, approximate,
// 50%-capped occupancy) with an exact decomposition. Per chunk of L=64:
// local zero-init scan gives c_k (local mean), g_k = x_k - c_k. Then
//   mu_out  = a^L mu_in + c_L
//   var_out = a^L var_in + P0 - 2(1-a)a^L mu_in G + a^(L+1)(1-a^L) mu_in^2
// with P0 = (1-a) sum a^(L-k) g_k^2, G = sum g_k  (cross-term weight
// a^(L-k)*a^k == a^L is constant -> only 3 aggregates/chunk needed).
// Pass1 computes aggregates (reads x once); tiny combine kernel chains
// 64 chunk states per (b,f); pass2 scans each chunk with its exact
// initial state (x re-read is L3-resident: 252MB < 256MB LLC) and
// writes y with non-temporal stores. Workspace: 5 planes ~= 19.7 MB.

#define ALPHA 0.99f
#define OMA   0.01f     // 1 - ALPHA
#define VAR0  1600.0f   // 40^2

constexpr int Bn = 32, Tn = 4096, Fn = 481;
constexpr int Cn = 64;           // chunks along T
constexpr int Ln = Tn / Cn;      // 64, chunk length
constexpr int U  = 16;           // prefetch depth
constexpr size_t PLANE = (size_t)Bn * Cn * Fn;   // floats per ws plane

// Combine constants (double-derived): AL = 0.99^64
#define AL   0.52559650f
#define P1C  0.01051193f   // 2*(1-a)*a^L
#define P2C  0.24685139f   // a^(L+1) * (1 - a^L)

__global__ __launch_bounds__(256) void pass1_kernel(
    const float* __restrict__ x, float* __restrict__ ws) {
  const int blk = blockIdx.x;
  const int h  = blk & 1;        // F-half: 0 -> [0,256), 1 -> [256,481)
  const int bc = blk >> 1;
  const int c  = bc & (Cn - 1);
  const int b  = bc >> 6;        // log2(Cn) = 6
  const int f  = h * 256 + threadIdx.x;
  const bool active = (f < Fn);
  const int fc = active ? f : (Fn - 1);

  const float* xp = x + ((size_t)b * Tn + (size_t)c * Ln) * Fn + fc;

  float cmu = 0.f, P0 = 0.f, G = 0.f;
  float xv[U], xn[U];
#pragma unroll
  for (int i = 0; i < U; ++i) xv[i] = xp[(size_t)i * Fn];

  for (int t = 0; t < Ln; t += U) {
    if (t + U < Ln) {
#pragma unroll
      for (int i = 0; i < U; ++i) xn[i] = xp[(size_t)(t + U + i) * Fn];
    }
#pragma unroll
    for (int i = 0; i < U; ++i) {
      const float xt = xv[i];
      cmu = fmaf(ALPHA, cmu, OMA * xt);   // local zero-init mean
      const float g = xt - cmu;
      G += g;
      P0 = fmaf(ALPHA, P0, OMA * (g * g));
    }
#pragma unroll
    for (int i = 0; i < U; ++i) xv[i] = xn[i];
  }

  if (active) {
    const size_t idx = ((size_t)b * Cn + c) * Fn + f;
    ws[idx]             = cmu;   // c_L plane
    ws[PLANE + idx]     = P0;    // P0 plane
    ws[2 * PLANE + idx] = G;     // G plane
  }
}

__global__ __launch_bounds__(256) void combine_kernel(
    const float* __restrict__ mu0, float* __restrict__ ws) {
  const int blk = blockIdx.x;
  const int h = blk & 1;
  const int b = blk >> 1;
  const int f = h * 256 + threadIdx.x;
  const bool active = (f < Fn);
  const int fc = active ? f : (Fn - 1);

  const float* cLp = ws;
  const float* P0p = ws + PLANE;
  const float* Gp  = ws + 2 * PLANE;
  float* muS  = ws + 3 * PLANE;
  float* varS = ws + 4 * PLANE;

  float mu  = mu0[b * Fn + fc];
  float var = VAR0;

  constexpr int P = 4;  // prefetch depth over chunks
  const size_t base = (size_t)b * Cn * Fn + fc;
  float cv[P], pv[P], gv[P];
#pragma unroll
  for (int i = 0; i < P; ++i) {
    const size_t idx = base + (size_t)i * Fn;
    cv[i] = cLp[idx]; pv[i] = P0p[idx]; gv[i] = Gp[idx];
  }

  for (int c = 0; c < Cn; c += P) {
    float cn[P], pn[P], gn[P];
    if (c + P < Cn) {
#pragma unroll
      for (int i = 0; i < P; ++i) {
        const size_t idx = base + (size_t)(c + P + i) * Fn;
        cn[i] = cLp[idx]; pn[i] = P0p[idx]; gn[i] = Gp[idx];
      }
    }
#pragma unroll
    for (int i = 0; i < P; ++i) {
      const size_t idx = base + (size_t)(c + i) * Fn;
      if (active) { muS[idx] = mu; varS[idx] = var; }
      const float mu_n = fmaf(AL, mu, cv[i]);
      var = fmaf(AL, var, pv[i] - P1C * mu * gv[i] + P2C * (mu * mu));
      mu = mu_n;
    }
#pragma unroll
    for (int i = 0; i < P; ++i) { cv[i] = cn[i]; pv[i] = pn[i]; gv[i] = gn[i]; }
  }
}

__global__ __launch_bounds__(256) void pass2_kernel(
    const float* __restrict__ x, const float* __restrict__ ws,
    float* __restrict__ out) {
  const int blk = blockIdx.x;
  const int h  = blk & 1;
  const int bc = blk >> 1;
  const int c  = bc & (Cn - 1);
  const int b  = bc >> 6;
  const int f  = h * 256 + threadIdx.x;
  const bool active = (f < Fn);
  const int fc = active ? f : (Fn - 1);

  const size_t sidx = ((size_t)b * Cn + c) * Fn + fc;
  float mu  = ws[3 * PLANE + sidx];   // exact state entering this chunk
  float var = ws[4 * PLANE + sidx];

  const float* xp = x + ((size_t)b * Tn + (size_t)c * Ln) * Fn + fc;
  float*       op = out + ((size_t)b * Tn + (size_t)c * Ln) * Fn + fc;

  float xv[U], xn[U];
#pragma unroll
  for (int i = 0; i < U; ++i) xv[i] = xp[(size_t)i * Fn];

  for (int t = 0; t < Ln; t += U) {
    if (t + U < Ln) {
#pragma unroll
      for (int i = 0; i < U; ++i) xn[i] = xp[(size_t)(t + U + i) * Fn];
    }
#pragma unroll
    for (int i = 0; i < U; ++i) {
      const float xt = xv[i];
      mu = fmaf(ALPHA, mu, OMA * xt);
      const float d = xt - mu;
      var = fmaf(ALPHA, var, OMA * (d * d));
      const float y = d * rsqrtf(var);  // eps=1e-12 negligible
      if (active) __builtin_nontemporal_store(y, &op[(size_t)(t + i) * Fn]);
    }
#pragma unroll
    for (int i = 0; i < U; ++i) xv[i] = xn[i];
  }
}

extern "C" void kernel_launch(void* const* d_in, const int* in_sizes, int n_in,
                              void* d_out, int out_size, void* d_ws, size_t ws_size,
                              hipStream_t stream) {
  const float* x   = (const float*)d_in[0];
  const float* mu0 = (const float*)d_in[1];
  float* out = (float*)d_out;
  float* ws  = (float*)d_ws;   // needs 5*PLANE*4 ~= 19.7 MB

  pass1_kernel<<<Bn * Cn * 2, 256, 0, stream>>>(x, ws);
  combine_kernel<<<Bn * 2, 256, 0, stream>>>(mu0, ws);
  pass2_kernel<<<Bn * Cn * 2, 256, 0, stream>>>(x, ws, out);
}